// Round 13
// baseline (319.682 us; speedup 1.0000x reference)
//
#include <hip/hip_runtime.h>

#pragma clang fp contract(off)

#define NBOX 8192
#define BLK  1024
#define EPT  8
#define NBUCK 4096
#define NB 256
#define IOU_THR 0.1f
#define NREP 2   // measurement: middle section runs twice (bit-identical result)

typedef unsigned short u16;
typedef unsigned int u32;
typedef unsigned long long u64;

// Exact division-free IoU threshold test (proven R8):
// round_f32(inter/u) >= 0.1f  <=>  inter > m*u, m = 0x1.999999p-4 (f64-exact).
#define MND 0x1.999999p-4

#define SMEM_TOT 161408

__global__ __launch_bounds__(BLK, 4) void nms_kernel(const float* __restrict__ in,
                                                     float* __restrict__ out) {
    __shared__ __align__(16) char smem[SMEM_TOT];
    const int img = blockIdx.x;
    const float* __restrict__ p = in + (size_t)img * 5 * NBOX;
    float* __restrict__ o = out + (size_t)img * 5 * NBOX;
    const int t = threadIdx.x;
    const int lane = t & 63;
    const int wid = t >> 6;

    // persistent LDS
    float4* box   = (float4*)smem;                 // 128 KB
    u16* A        = (u16*)(smem + 131072);         // 16 KB
    float4* bx    = (float4*)(smem + 147456);      // 4 KB
    u64 (*mat)[4] = (u64(*)[4])(smem + 151552);    // 8 KB
    float4* kx    = (float4*)(smem + 155648);      // overlay mat rows 128..255
    u32* pfxA     = (u32*)(smem + 151552);         // alias mat (post-loop only)
    u32* kom      = (u32*)(smem + 159744);         // 1 KB
    int* wcnt     = (int*)(smem + 160768);         // 64 B
    u64* keptQ    = (u64*)(smem + 160832);         // 32 B
    int* S0sh     = (int*)(smem + 160864);
    // sort workspace overlaying box[]
    u64* skey  = (u64*)smem;                       // 64 KB
    u32* hist  = (u32*)(smem + 65536);             // 16 KB
    u32* bbase = (u32*)(smem + 81920);             // 16 KB

    // ---- zero output up front ----
    {
        float4 z; z.x = z.y = z.z = z.w = 0.0f;
        float4* o4 = (float4*)o;
#pragma unroll
        for (int e = 0; e < 10; e++) o4[t + e * BLK] = z;
    }

    for (int rep = 0; rep < NREP; rep++) {
        // ---- init ----
        for (int i = t; i < NBUCK; i += BLK) hist[i] = 0;
        if (t < 256) kom[t] = 0;
        if (t == 0) *S0sh = 0;
        __syncthreads();

        // ---- sort pass 1: bucket + arrival order ----
        u32 mybkt[EPT], myarr[EPT], mykeyhi[EPT];
#pragma unroll
        for (int e = 0; e < EPT; e++) {
            int j = t + e * BLK;
            float s = p[4 * NBOX + j];
            u32 u = __float_as_uint(s);
            u32 ordb = u ^ (u32)(((int)u >> 31) | (int)0x80000000);
            mykeyhi[e] = ~ordb;
            int vb = (int)(s * (float)NBUCK);
            vb = vb < 0 ? 0 : (vb > NBUCK - 1 ? NBUCK - 1 : vb);
            mybkt[e] = (u32)(NBUCK - 1 - vb);
            myarr[e] = atomicAdd(&hist[mybkt[e]], 1u);
            u64 bal = __ballot(s > 0.0f);
            if (lane == 0) atomicAdd(S0sh, (int)__popcll(bal));
        }
        __syncthreads();

        // ---- exclusive scan over hist (4 bins/thread) ----
        {
            u32 h0 = hist[4 * t], h1 = hist[4 * t + 1], h2 = hist[4 * t + 2], h3 = hist[4 * t + 3];
            int v = (int)(h0 + h1 + h2 + h3);
            int x = v;
            for (int d = 1; d < 64; d <<= 1) {
                int y = __shfl_up(x, d, 64);
                if (lane >= d) x += y;
            }
            if (lane == 63) wcnt[wid] = x;
            __syncthreads();
            int wb = 0;
            for (int i = 0; i < wid; i++) wb += wcnt[i];
            int excl = wb + x - v;
            bbase[4 * t]     = (u32)excl;
            bbase[4 * t + 1] = (u32)excl + h0;
            bbase[4 * t + 2] = (u32)excl + h0 + h1;
            bbase[4 * t + 3] = (u32)excl + h0 + h1 + h2;
        }
        __syncthreads();

        // ---- scatter keys ----
#pragma unroll
        for (int e = 0; e < EPT; e++) {
            u32 pos = bbase[mybkt[e]] + myarr[e];
            skey[pos] = ((u64)mykeyhi[e] << 32) | (u32)(t + e * BLK);
        }
        __syncthreads();

        // ---- rank within bucket -> A[rank] = orig idx ----
#pragma unroll
        for (int e = 0; e < EPT; e++) {
            u32 b = mybkt[e];
            u32 lo = bbase[b], hi2 = lo + hist[b];
            u64 me = ((u64)mykeyhi[e] << 32) | (u32)(t + e * BLK);
            u32 r = lo;
            for (u32 q = lo; q < hi2; q++) r += (skey[q] < me) ? 1u : 0u;
            A[r] = (u16)(t + e * BLK);
        }
        __syncthreads();
        int S = *S0sh;

        // ---- fill box[] ----
#pragma unroll
        for (int e = 0; e < EPT; e++) {
            int j = t + e * BLK;
            float cx = p[j], cy = p[NBOX + j];
            float w_ = p[2 * NBOX + j], h_ = p[3 * NBOX + j];
            box[j] = make_float4(cx - w_ * 0.5f, cy - h_ * 0.5f,
                                 cx + w_ * 0.5f, cy + h_ * 0.5f);
        }
        __syncthreads();

        // ---- stage initial batch coords + zero mat ----
        if (t < NB) bx[t] = box[A[t]];
        ((u64*)mat)[t] = 0;
        __syncthreads();

        // ---- batched greedy loop ----
        while (S > 0) {
            int nb = S < NB ? S : NB;

            // (E) balanced lower-triangle matrix (proven exact R9-R12)
            {
                int i = t >> 2, q = t & 3;
                if (i > 0 && i < nb) {
                    int clo = (i * q) >> 2;
                    int chi = (i * (q + 1)) >> 2;
                    if (chi > clo) {
                        float4 bi = bx[i];
                        float ari = (bi.z - bi.x) * (bi.w - bi.y);
                        u64 acc = 0;
                        for (int c = clo; c < chi; c++) {
                            float4 bc = bx[c];
                            float arc = (bc.z - bc.x) * (bc.w - bc.y);
                            float iw = fmaxf(fminf(bi.z, bc.z) - fmaxf(bi.x, bc.x), 0.0f);
                            float ih = fmaxf(fminf(bi.w, bc.w) - fmaxf(bi.y, bc.y), 0.0f);
                            float inter = iw * ih;
                            float t2 = (ari + arc) - inter;
                            float uu = t2 + 1e-8f;
                            if ((double)inter > MND * (double)uu) acc |= (1ull << (c - clo));
                        }
                        if (acc) {
                            int w0 = clo >> 6, sh = clo & 63;
                            atomicOr(&mat[i][w0], acc << sh);
                            if (sh && (((chi - 1) >> 6) != w0))
                                atomicOr(&mat[i][w0 + 1], acc >> (64 - sh));
                        }
                    }
                }
            }
            __syncthreads();  // B1

            // (G) wave 0: closure + apply + remainder load || waves 1-15: tail load
            int tailN = S - nb;
            int C1 = 0, base0 = nb;
            if (tailN > 0) {
                int lim = tailN < 7680 ? tailN : 7680;
                C1 = (lim + 959) / 960;
                base0 = nb + 960 * C1;
            }
            float4 eb[EPT]; float ea[EPT]; u16 ei[EPT];
            u32 am = 0;
            if (wid == 0) {
                u64 r0[4], r1[4], r2[4], r3[4];
#pragma unroll
                for (int wq = 0; wq < 4; wq++) {
                    r0[wq] = mat[lane][wq];
                    r1[wq] = mat[64 + lane][wq];
                    r2[wq] = mat[128 + lane][wq];
                    r3[wq] = mat[192 + lane][wq];
                }
                u64 A0, A1, A2, A3;
                {
                    int n0 = nb;       A0 = n0 <= 0 ? 0ull : (n0 >= 64 ? ~0ull : ((1ull << n0) - 1ull));
                    int n1 = nb - 64;  A1 = n1 <= 0 ? 0ull : (n1 >= 64 ? ~0ull : ((1ull << n1) - 1ull));
                    int n2 = nb - 128; A2 = n2 <= 0 ? 0ull : (n2 >= 64 ? ~0ull : ((1ull << n2) - 1ull));
                    int n3 = nb - 192; A3 = n3 <= 0 ? 0ull : (n3 >= 64 ? ~0ull : ((1ull << n3) - 1ull));
                }
                u64 K0 = 0, K1 = 0, K2 = 0, K3 = 0;
                u64 lm = (1ull << lane) - 1ull;
                while (A0 | A1 | A2 | A3) {
                    bool c0b = ((A0 >> lane) & 1) && !(r0[0] & A0 & lm);
                    bool c1b = ((A1 >> lane) & 1) && !((r1[0] & A0) | (r1[1] & A1 & lm));
                    bool c2b = ((A2 >> lane) & 1) && !((r2[0] & A0) | (r2[1] & A1) | (r2[2] & A2 & lm));
                    bool c3b = ((A3 >> lane) & 1) && !((r3[0] & A0) | (r3[1] & A1) | (r3[2] & A2) | (r3[3] & A3 & lm));
                    u64 C0_ = __ballot(c0b), C1_ = __ballot(c1b), C2_ = __ballot(c2b), C3_ = __ballot(c3b);
                    K0 |= C0_; K1 |= C1_; K2 |= C2_; K3 |= C3_;
                    A0 &= ~C0_; A1 &= ~C1_; A2 &= ~C2_; A3 &= ~C3_;
                    bool s0b = ((A0 >> lane) & 1) && ((r0[0] & C0_) | (r0[1] & C1_) | (r0[2] & C2_) | (r0[3] & C3_));
                    bool s1b = ((A1 >> lane) & 1) && ((r1[0] & C0_) | (r1[1] & C1_) | (r1[2] & C2_) | (r1[3] & C3_));
                    bool s2b = ((A2 >> lane) & 1) && ((r2[0] & C0_) | (r2[1] & C1_) | (r2[2] & C2_) | (r2[3] & C3_));
                    bool s3b = ((A3 >> lane) & 1) && ((r3[0] & C0_) | (r3[1] & C1_) | (r3[2] & C2_) | (r3[3] & C3_));
                    A0 &= ~__ballot(s0b); A1 &= ~__ballot(s1b); A2 &= ~__ballot(s2b); A3 &= ~__ballot(s3b);
                }
                if (lane < 4) keptQ[lane] = lane == 0 ? K0 : lane == 1 ? K1 : lane == 2 ? K2 : K3;
                {
                    int pkb1 = (int)__popcll(K0);
                    int pkb2 = pkb1 + (int)__popcll(K1);
                    int pkb3 = pkb2 + (int)__popcll(K2);
#pragma unroll
                    for (int wq = 0; wq < 4; wq++) {
                        u64 kq = wq == 0 ? K0 : wq == 1 ? K1 : wq == 2 ? K2 : K3;
                        if ((kq >> lane) & 1) {
                            int slot = wq * 64 + lane;
                            int j = (int)A[slot];
                            atomicOr(&kom[j >> 5], 1u << (j & 31));
                            int pk = (wq == 0 ? 0 : wq == 1 ? pkb1 : wq == 2 ? pkb2 : pkb3)
                                     + (int)__popcll(kq & lm);
                            kx[pk] = bx[slot];
                        }
                    }
                }
                if (base0 < S) {
                    int C0 = (S - base0 + 63) >> 6;
                    int st0 = base0 + lane * C0;
#pragma unroll
                    for (int e = 0; e < EPT; e++) {
                        int pos = st0 + e;
                        if (e < C0 && pos < S) {
                            u16 j = A[pos];
                            ei[e] = j;
                            float4 b = box[j];
                            eb[e] = b;
                            ea[e] = (b.z - b.x) * (b.w - b.y);
                            am |= (1u << e);
                        }
                    }
                }
            } else {
                int ti = t - 64;
                int st = nb + ti * C1;
#pragma unroll
                for (int e = 0; e < EPT; e++) {
                    int pos = st + e;
                    if (e < C1 && pos < S) {
                        u16 j = A[pos];
                        ei[e] = j;
                        float4 b = box[j];
                        eb[e] = b;
                        ea[e] = (b.z - b.x) * (b.w - b.y);
                        am |= (1u << e);
                    }
                }
            }
            __syncthreads();  // B2

            if (t < 512) ((u64*)mat)[t] = 0;
            u64 kq0 = keptQ[0], kq1 = keptQ[1], kq2 = keptQ[2], kq3 = keptQ[3];
            int nk = (int)(__popcll(kq0) + __popcll(kq1) + __popcll(kq2) + __popcll(kq3));

            // (K) tail suppression
            if (am) {
                for (int c = 0; c < nk; c++) {
                    float4 cb = kx[c];
                    float arc = (cb.z - cb.x) * (cb.w - cb.y);
#pragma unroll
                    for (int e = 0; e < EPT; e++) {
                        if (am & (1u << e)) {
                            float iw = fminf(eb[e].z, cb.z) - fmaxf(eb[e].x, cb.x);
                            float ih = fminf(eb[e].w, cb.w) - fmaxf(eb[e].y, cb.y);
                            if (iw > 0.0f && ih > 0.0f) {
                                float inter = iw * ih;
                                float t2 = (ea[e] + arc) - inter;
                                float uu = t2 + 1e-8f;
                                if ((double)inter > MND * (double)uu) am &= ~(1u << e);
                            }
                        }
                    }
                    if (!am) break;
                }
            }

            // compaction (wave 0 counted last — holds top ranks)
            {
                int cnt = __popc(am);
                int x = cnt;
                for (int d = 1; d < 64; d <<= 1) {
                    int y = __shfl_up(x, d, 64);
                    if (lane >= d) x += y;
                }
                if (lane == 63) wcnt[wid] = x;
                __syncthreads();  // B4
                int wb = 0, tot = 0;
                for (int i = 0; i < 16; i++) tot += wcnt[i];
                if (wid == 0) {
                    for (int i = 1; i < 16; i++) wb += wcnt[i];
                } else {
                    for (int i = 1; i < wid; i++) wb += wcnt[i];
                }
                int off = wb + x - cnt;
#pragma unroll
                for (int e = 0; e < EPT; e++) {
                    if (am & (1u << e)) {
                        A[off] = ei[e];
                        if (off < NB) bx[off] = eb[e];
                        off++;
                    }
                }
                if (t >= 512) ((u64*)mat)[t] = 0;
                __syncthreads();  // B5
                S = tot;
            }
        }
        __syncthreads();  // end of rep: all loop reads of box/A done
    }

    // ---- output: prefix over kom, scatter kept columns ----
    {
        u32 w = (t < 256) ? kom[t] : 0u;
        int c = __popc(w);
        int x = c;
        for (int d = 1; d < 64; d <<= 1) {
            int y = __shfl_up(x, d, 64);
            if (lane >= d) x += y;
        }
        if (lane == 63) wcnt[wid] = x;
        __syncthreads();
        int wb = 0;
        for (int i = 0; i < wid; i++) wb += wcnt[i];
        if (t < 256) pfxA[t] = (u32)(wb + x - c);
    }
    __syncthreads();
    for (int j = t; j < NBOX; j += BLK) {
        u32 km = kom[j >> 5];
        if ((km >> (j & 31)) & 1u) {
            int pos = (int)(pfxA[j >> 5] + (u32)__popc(km & ((1u << (j & 31)) - 1u)));
            o[0 * NBOX + pos] = p[0 * NBOX + j];
            o[1 * NBOX + pos] = p[1 * NBOX + j];
            o[2 * NBOX + pos] = p[2 * NBOX + j];
            o[3 * NBOX + pos] = p[3 * NBOX + j];
            o[4 * NBOX + pos] = p[4 * NBOX + j];
        }
    }
}

extern "C" void kernel_launch(void* const* d_in, const int* in_sizes, int n_in,
                              void* d_out, int out_size, void* d_ws, size_t ws_size,
                              hipStream_t stream) {
    const float* in = (const float*)d_in[0];
    float* out = (float*)d_out;
    int B = in_sizes[0] / (5 * NBOX);
    hipLaunchKernelGGL(nms_kernel, dim3(B), dim3(BLK), 0, stream, in, out);
}

// Round 14
// 225.799 us; speedup vs baseline: 1.4158x; 1.4158x over previous
//
#include <hip/hip_runtime.h>

#pragma clang fp contract(off)

#define NBOX 8192
#define BLK  1024
#define EPT  8
#define NBUCK 4096
#define NB 256

typedef unsigned short u16;
typedef unsigned int u32;
typedef unsigned long long u64;

// Exact division-free IoU threshold test (proven R8):
// round_f32(inter/u) >= 0.1f  <=>  inter > m*u, m = 0x1.999999p-4 (f64-exact).
#define MND 0x1.999999p-4

#define SMEM_TOT 148736

__global__ __launch_bounds__(BLK, 4) void nms_kernel(const float* __restrict__ in,
                                                     float* __restrict__ out) {
    __shared__ __align__(16) char smem[SMEM_TOT];
    const int img = blockIdx.x;
    const float* __restrict__ p = in + (size_t)img * 5 * NBOX;
    float* __restrict__ o = out + (size_t)img * 5 * NBOX;
    const int t = threadIdx.x;
    const int lane = t & 63;
    const int wid = t >> 6;

    // ---- LDS overlays on [0,128K) ----
    u64* skey  = (u64*)smem;                     // sort: 64 KB
    u32* hist  = (u32*)(smem + 65536);           // sort: 16 KB
    u32* bbase = (u32*)(smem + 81920);           // sort: 16 KB
    float4* box = (float4*)smem;                 // post-sort: 128 KB (dead after gather)
    float4* bx  = (float4*)smem;                 // loop: 4 KB batch coords
    float* ka   = (float*)(smem + 4608);         // loop: 1 KB kept areas
    float4* kx  = (float4*)(smem + 5632);        // loop: 4 KB kept coords
    u64 (*mat)[4] = (u64(*)[4])(smem + 9728);    // loop: 8 KB lower-tri bits
    u32* pfxA   = (u32*)(smem + 17920);          // output: 1 KB
    // ---- persistent high region ----
    u16* sidx  = (u16*)(smem + 131072);          // 16 KB: rank -> orig idx
    u32* kom   = (u32*)(smem + 147456);          // 1 KB: kept bitmask by orig idx
    int* wcnt  = (int*)(smem + 148480);          // 64 B
    u64* keptQ = (u64*)(smem + 148544);          // 32 B
    int* S0sh  = (int*)(smem + 148576);

    // ---- zero output up front (stores drain under the sort) ----
    {
        float4 z; z.x = z.y = z.z = z.w = 0.0f;
        float4* o4 = (float4*)o;
#pragma unroll
        for (int e = 0; e < 10; e++) o4[t + e * BLK] = z;
    }

    // ---- init ----
    for (int i = t; i < NBUCK; i += BLK) hist[i] = 0;
    if (t < 256) kom[t] = 0;
    if (t == 0) *S0sh = 0;
    __syncthreads();

    // ---- sort pass 1: bucket + arrival order ----
    u32 mybkt[EPT], myarr[EPT], mykeyhi[EPT];
#pragma unroll
    for (int e = 0; e < EPT; e++) {
        int j = t + e * BLK;
        float s = p[4 * NBOX + j];
        u32 u = __float_as_uint(s);
        u32 ordb = u ^ (u32)(((int)u >> 31) | (int)0x80000000);
        mykeyhi[e] = ~ordb;                      // ascending == score desc
        int vb = (int)(s * (float)NBUCK);
        vb = vb < 0 ? 0 : (vb > NBUCK - 1 ? NBUCK - 1 : vb);
        mybkt[e] = (u32)(NBUCK - 1 - vb);
        myarr[e] = atomicAdd(&hist[mybkt[e]], 1u);
        u64 bal = __ballot(s > 0.0f);
        if (lane == 0) atomicAdd(S0sh, (int)__popcll(bal));
    }
    __syncthreads();

    // ---- exclusive scan over hist (4 bins/thread) ----
    {
        u32 h0 = hist[4 * t], h1 = hist[4 * t + 1], h2 = hist[4 * t + 2], h3 = hist[4 * t + 3];
        int v = (int)(h0 + h1 + h2 + h3);
        int x = v;
        for (int d = 1; d < 64; d <<= 1) {
            int y = __shfl_up(x, d, 64);
            if (lane >= d) x += y;
        }
        if (lane == 63) wcnt[wid] = x;
        __syncthreads();
        int wb = 0;
        for (int i = 0; i < wid; i++) wb += wcnt[i];
        int excl = wb + x - v;
        bbase[4 * t]     = (u32)excl;
        bbase[4 * t + 1] = (u32)excl + h0;
        bbase[4 * t + 2] = (u32)excl + h0 + h1;
        bbase[4 * t + 3] = (u32)excl + h0 + h1 + h2;
    }
    __syncthreads();

    // ---- scatter keys ----
#pragma unroll
    for (int e = 0; e < EPT; e++) {
        u32 pos = bbase[mybkt[e]] + myarr[e];
        skey[pos] = ((u64)mykeyhi[e] << 32) | (u32)(t + e * BLK);
    }
    __syncthreads();

    // ---- rank within bucket -> sidx[rank] = orig idx ----
#pragma unroll
    for (int e = 0; e < EPT; e++) {
        u32 b = mybkt[e];
        u32 lo = bbase[b], hi2 = lo + hist[b];
        u64 me = ((u64)mykeyhi[e] << 32) | (u32)(t + e * BLK);
        u32 r = lo;
        for (u32 q = lo; q < hi2; q++) r += (skey[q] < me) ? 1u : 0u;
        sidx[r] = (u16)(t + e * BLK);
    }
    __syncthreads();   // sort workspace dead
    int S0 = *S0sh;

    // ---- fill box[] (coalesced) ----
#pragma unroll
    for (int e = 0; e < EPT; e++) {
        int j = t + e * BLK;
        float cx = p[j], cy = p[NBOX + j];
        float w_ = p[2 * NBOX + j], h_ = p[3 * NBOX + j];
        box[j] = make_float4(cx - w_ * 0.5f, cy - h_ * 0.5f,
                             cx + w_ * 0.5f, cy + h_ * 0.5f);
    }
    __syncthreads();

    // ---- one-time gather: thread t owns ranks t*8+e (coords in registers) ----
    float4 eb[EPT]; float ea[EPT];
    u32 am = 0;
#pragma unroll
    for (int e = 0; e < EPT; e++) {
        int r = t * EPT + e;
        float4 b = box[sidx[r]];
        eb[e] = b;
        ea[e] = (b.z - b.x) * (b.w - b.y);
        if (r < S0) am |= (1u << e);
    }
    __syncthreads();   // box dead; [0,128K) reusable
    ((u64*)mat)[t] = 0;   // zero mat (1024 u64 = 8 KB); ordered by B0 below

    // ---- persistent-ownership greedy loop ----
    while (true) {
        // (A) scan alive counts
        int myAlive = __popc(am);
        int x = myAlive;
        for (int d = 1; d < 64; d <<= 1) {
            int y = __shfl_up(x, d, 64);
            if (lane >= d) x += y;
        }
        if (lane == 63) wcnt[wid] = x;
        __syncthreads();  // B0
        int wb = 0, S = 0;
        for (int i = 0; i < 16; i++) {
            int v = wcnt[i];
            if (i < wid) wb += v;
            S += v;
        }
        if (S == 0) break;
        int nb = S < NB ? S : NB;
        int r = wb + x - myAlive;   // exclusive alive-prefix (rank order)

        // (X) extract top-256 alive into bx from registers; pack slots 16-bit
        u64 spl = 0, sph = 0;
#pragma unroll
        for (int e = 0; e < EPT; e++) {
            if (am & (1u << e)) {
                if (r < NB) {
                    bx[r] = eb[e];
                    u64 v = (u64)(u32)(r + 1) << (16 * (e & 3));
                    if (e < 4) spl |= v; else sph |= v;
                    am &= ~(1u << e);   // batch members are decided this iter
                }
                r++;
            }
        }
        __syncthreads();  // B1: bx visible

        // (E) balanced lower-triangle matrix (proven exact R9-R13)
        {
            int i = t >> 2, q = t & 3;
            if (i > 0 && i < nb) {
                int clo = (i * q) >> 2;
                int chi = (i * (q + 1)) >> 2;
                if (chi > clo) {
                    float4 bi = bx[i];
                    float ari = (bi.z - bi.x) * (bi.w - bi.y);
                    u64 acc = 0;
                    for (int c = clo; c < chi; c++) {
                        float4 bc = bx[c];
                        float arc = (bc.z - bc.x) * (bc.w - bc.y);
                        float iw = fmaxf(fminf(bi.z, bc.z) - fmaxf(bi.x, bc.x), 0.0f);
                        float ih = fmaxf(fminf(bi.w, bc.w) - fmaxf(bi.y, bc.y), 0.0f);
                        float inter = iw * ih;
                        float t2 = (ari + arc) - inter;
                        float uu = t2 + 1e-8f;
                        if ((double)inter > MND * (double)uu) acc |= (1ull << (c - clo));
                    }
                    if (acc) {
                        int w0 = clo >> 6, sh = clo & 63;
                        atomicOr(&mat[i][w0], acc << sh);
                        if (sh && (((chi - 1) >> 6) != w0))
                            atomicOr(&mat[i][w0 + 1], acc >> (64 - sh));
                    }
                }
            }
        }
        __syncthreads();  // B2

        // (G) wave 0: closure resolve (exact greedy on batch, proven R3-R13)
        if (wid == 0) {
            u64 r0[4], r1[4], r2[4], r3[4];
#pragma unroll
            for (int wq = 0; wq < 4; wq++) {
                r0[wq] = mat[lane][wq];
                r1[wq] = mat[64 + lane][wq];
                r2[wq] = mat[128 + lane][wq];
                r3[wq] = mat[192 + lane][wq];
            }
            u64 A0, A1, A2, A3;
            {
                int n0 = nb;       A0 = n0 <= 0 ? 0ull : (n0 >= 64 ? ~0ull : ((1ull << n0) - 1ull));
                int n1 = nb - 64;  A1 = n1 <= 0 ? 0ull : (n1 >= 64 ? ~0ull : ((1ull << n1) - 1ull));
                int n2 = nb - 128; A2 = n2 <= 0 ? 0ull : (n2 >= 64 ? ~0ull : ((1ull << n2) - 1ull));
                int n3 = nb - 192; A3 = n3 <= 0 ? 0ull : (n3 >= 64 ? ~0ull : ((1ull << n3) - 1ull));
            }
            u64 K0 = 0, K1 = 0, K2 = 0, K3 = 0;
            u64 lm = (1ull << lane) - 1ull;
            while (A0 | A1 | A2 | A3) {
                bool c0b = ((A0 >> lane) & 1) && !(r0[0] & A0 & lm);
                bool c1b = ((A1 >> lane) & 1) && !((r1[0] & A0) | (r1[1] & A1 & lm));
                bool c2b = ((A2 >> lane) & 1) && !((r2[0] & A0) | (r2[1] & A1) | (r2[2] & A2 & lm));
                bool c3b = ((A3 >> lane) & 1) && !((r3[0] & A0) | (r3[1] & A1) | (r3[2] & A2) | (r3[3] & A3 & lm));
                u64 C0_ = __ballot(c0b), C1_ = __ballot(c1b), C2_ = __ballot(c2b), C3_ = __ballot(c3b);
                K0 |= C0_; K1 |= C1_; K2 |= C2_; K3 |= C3_;
                A0 &= ~C0_; A1 &= ~C1_; A2 &= ~C2_; A3 &= ~C3_;
                bool s0b = ((A0 >> lane) & 1) && ((r0[0] & C0_) | (r0[1] & C1_) | (r0[2] & C2_) | (r0[3] & C3_));
                bool s1b = ((A1 >> lane) & 1) && ((r1[0] & C0_) | (r1[1] & C1_) | (r1[2] & C2_) | (r1[3] & C3_));
                bool s2b = ((A2 >> lane) & 1) && ((r2[0] & C0_) | (r2[1] & C1_) | (r2[2] & C2_) | (r2[3] & C3_));
                bool s3b = ((A3 >> lane) & 1) && ((r3[0] & C0_) | (r3[1] & C1_) | (r3[2] & C2_) | (r3[3] & C3_));
                A0 &= ~__ballot(s0b); A1 &= ~__ballot(s1b); A2 &= ~__ballot(s2b); A3 &= ~__ballot(s3b);
            }
            if (lane < 4) keptQ[lane] = lane == 0 ? K0 : lane == 1 ? K1 : lane == 2 ? K2 : K3;
        }
        __syncthreads();  // B3: keptQ visible

        // (I) apply by owner threads (registers -> kx/ka, kom via one sidx read)
        u64 kq0 = keptQ[0], kq1 = keptQ[1], kq2 = keptQ[2], kq3 = keptQ[3];
        int nk = (int)(__popcll(kq0) + __popcll(kq1) + __popcll(kq2) + __popcll(kq3));
        {
            int pkb1 = (int)__popcll(kq0);
            int pkb2 = pkb1 + (int)__popcll(kq1);
            int pkb3 = pkb2 + (int)__popcll(kq2);
#pragma unroll
            for (int e = 0; e < EPT; e++) {
                int se = (int)(((e < 4 ? spl : sph) >> (16 * (e & 3))) & 0xFFFF);
                if (se) {
                    int slot = se - 1;
                    int wq = slot >> 6;
                    u64 kq = wq == 0 ? kq0 : wq == 1 ? kq1 : wq == 2 ? kq2 : kq3;
                    if ((kq >> (slot & 63)) & 1) {
                        int oi = (int)sidx[t * EPT + e];
                        atomicOr(&kom[oi >> 5], 1u << (oi & 31));
                        int pk = (wq == 0 ? 0 : wq == 1 ? pkb1 : wq == 2 ? pkb2 : pkb3)
                                 + (int)__popcll(kq & ((1ull << (slot & 63)) - 1ull));
                        kx[pk] = eb[e];
                        ka[pk] = ea[e];
                    }
                }
            }
        }
        ((u64*)mat)[t] = 0;   // zero mat for next iter (closure reads done at B3)
        __syncthreads();  // B4: kx/ka visible

        // (K) tail suppression: registers vs broadcast kx/ka, early break
        if (am) {
            for (int c = 0; c < nk; c++) {
                float4 cb = kx[c];
                float arc = ka[c];
#pragma unroll
                for (int e = 0; e < EPT; e++) {
                    if (am & (1u << e)) {
                        float iw = fminf(eb[e].z, cb.z) - fmaxf(eb[e].x, cb.x);
                        float ih = fminf(eb[e].w, cb.w) - fmaxf(eb[e].y, cb.y);
                        if (iw > 0.0f && ih > 0.0f) {
                            float inter = iw * ih;
                            float t2 = (ea[e] + arc) - inter;
                            float uu = t2 + 1e-8f;
                            if ((double)inter > MND * (double)uu) am &= ~(1u << e);
                        }
                    }
                }
                if (!am) break;
            }
        }
    }
    __syncthreads();  // wcnt reuse below

    // ---- output: prefix over kom, scatter kept columns (pre-zeroed at entry) ----
    {
        u32 w = (t < 256) ? kom[t] : 0u;
        int c = __popc(w);
        int x = c;
        for (int d = 1; d < 64; d <<= 1) {
            int y = __shfl_up(x, d, 64);
            if (lane >= d) x += y;
        }
        if (lane == 63) wcnt[wid] = x;
        __syncthreads();
        int wb = 0;
        for (int i = 0; i < wid; i++) wb += wcnt[i];
        if (t < 256) pfxA[t] = (u32)(wb + x - c);
    }
    __syncthreads();
    for (int j = t; j < NBOX; j += BLK) {
        u32 km = kom[j >> 5];
        if ((km >> (j & 31)) & 1u) {
            int pos = (int)(pfxA[j >> 5] + (u32)__popc(km & ((1u << (j & 31)) - 1u)));
            o[0 * NBOX + pos] = p[0 * NBOX + j];
            o[1 * NBOX + pos] = p[1 * NBOX + j];
            o[2 * NBOX + pos] = p[2 * NBOX + j];
            o[3 * NBOX + pos] = p[3 * NBOX + j];
            o[4 * NBOX + pos] = p[4 * NBOX + j];
        }
    }
}

extern "C" void kernel_launch(void* const* d_in, const int* in_sizes, int n_in,
                              void* d_out, int out_size, void* d_ws, size_t ws_size,
                              hipStream_t stream) {
    const float* in = (const float*)d_in[0];
    float* out = (float*)d_out;
    int B = in_sizes[0] / (5 * NBOX);
    hipLaunchKernelGGL(nms_kernel, dim3(B), dim3(BLK), 0, stream, in, out);
}

// Round 15
// 153.330 us; speedup vs baseline: 2.0849x; 1.4726x over previous
//
#include <hip/hip_runtime.h>

#pragma clang fp contract(off)

#define NBOX 8192
#define BLK  1024
#define EPT  8
#define NBUCK 8192
#define NB 256

typedef unsigned short u16;
typedef unsigned int u32;
typedef unsigned long long u64;

// Exact division-free IoU threshold test (proven R8):
// round_f32(inter/u) >= 0.1f  <=>  inter > m*u, m = 0x1.999999p-4 (f64-exact).
#define MND 0x1.999999p-4

#define SMEM_TOT 162944

__global__ __launch_bounds__(BLK, 4) void nms_kernel(const float* __restrict__ in,
                                                     float* __restrict__ out) {
    __shared__ __align__(16) char smem[SMEM_TOT];
    const int img = blockIdx.x;
    const float* __restrict__ p = in + (size_t)img * 5 * NBOX;
    float* __restrict__ o = out + (size_t)img * 5 * NBOX;
    const int t = threadIdx.x;
    const int lane = t & 63;
    const int wid = t >> 6;

    // persistent LDS
    float4* box   = (float4*)smem;                 // 128 KB: x1,y1,x2,y2 by orig idx
    u16* A        = (u16*)(smem + 131072);         // 16 KB: alive list (orig idx, rank order)
    float4* bx    = (float4*)(smem + 147456);      // 4 KB: staged batch coords (compact)
    u64 (*mat)[4] = (u64(*)[4])(smem + 151552);    // 8 KB: 256x256 lower-tri bits
    float4* kx    = (float4*)(smem + 155648);      // overlay mat rows 128..255: kept coords
    u32* pfxA     = (u32*)(smem + 151552);         // alias mat (post-loop only)
    u32* kom      = (u32*)(smem + 159744);         // 1 KB: kept bitmask by orig idx
    int* wcnt     = (int*)(smem + 160768);         // 64 B
    u64* keptQ    = (u64*)(smem + 160832);         // 32 B
    int* S0sh     = (int*)(smem + 160864);
    float* barea  = (float*)(smem + 160896);       // 1 KB: batch areas
    float* ka     = (float*)(smem + 161920);       // 1 KB: kept areas
    // sort workspace overlaying box[] (dead after ranking)
    u64* skey  = (u64*)smem;                       // 64 KB
    u32* hist  = (u32*)(smem + 65536);             // 32 KB (8192 buckets)
    u32* bbase = (u32*)(smem + 98304);             // 32 KB

    // ---- zero output up front (stores drain under the sort) ----
    {
        float4 z; z.x = z.y = z.z = z.w = 0.0f;
        float4* o4 = (float4*)o;
#pragma unroll
        for (int e = 0; e < 10; e++) o4[t + e * BLK] = z;
    }

    // ---- init ----
    for (int i = t; i < NBUCK; i += BLK) hist[i] = 0;
    if (t < 256) kom[t] = 0;
    if (t == 0) *S0sh = 0;
    __syncthreads();

    // ---- sort pass 1: bucket + arrival order ----
    u32 mybkt[EPT], myarr[EPT], mykeyhi[EPT];
#pragma unroll
    for (int e = 0; e < EPT; e++) {
        int j = t + e * BLK;
        float s = p[4 * NBOX + j];
        u32 u = __float_as_uint(s);
        u32 ordb = u ^ (u32)(((int)u >> 31) | (int)0x80000000);
        mykeyhi[e] = ~ordb;                        // ascending == score desc
        int vb = (int)(s * (float)NBUCK);
        vb = vb < 0 ? 0 : (vb > NBUCK - 1 ? NBUCK - 1 : vb);
        mybkt[e] = (u32)(NBUCK - 1 - vb);
        myarr[e] = atomicAdd(&hist[mybkt[e]], 1u);
        u64 bal = __ballot(s > 0.0f);
        if (lane == 0) atomicAdd(S0sh, (int)__popcll(bal));
    }
    __syncthreads();

    // ---- exclusive scan over hist (8 bins/thread) ----
    {
        u32 h[8];
        int v = 0;
#pragma unroll
        for (int e = 0; e < 8; e++) { h[e] = hist[8 * t + e]; v += (int)h[e]; }
        int x = v;
        for (int d = 1; d < 64; d <<= 1) {
            int y = __shfl_up(x, d, 64);
            if (lane >= d) x += y;
        }
        if (lane == 63) wcnt[wid] = x;
        __syncthreads();
        int wb = 0;
        for (int i = 0; i < wid; i++) wb += wcnt[i];
        u32 run = (u32)(wb + x - v);
#pragma unroll
        for (int e = 0; e < 8; e++) { bbase[8 * t + e] = run; run += h[e]; }
    }
    __syncthreads();

    // ---- scatter keys ----
#pragma unroll
    for (int e = 0; e < EPT; e++) {
        u32 pos = bbase[mybkt[e]] + myarr[e];
        skey[pos] = ((u64)mykeyhi[e] << 32) | (u32)(t + e * BLK);
    }
    __syncthreads();

    // ---- rank within bucket -> A[rank] = orig idx ----
#pragma unroll
    for (int e = 0; e < EPT; e++) {
        u32 b = mybkt[e];
        u32 lo = bbase[b], hi2 = lo + hist[b];
        u64 me = ((u64)mykeyhi[e] << 32) | (u32)(t + e * BLK);
        u32 r = lo;
        for (u32 q = lo; q < hi2; q++) r += (skey[q] < me) ? 1u : 0u;
        A[r] = (u16)(t + e * BLK);
    }
    __syncthreads();   // sort workspace dead after this
    int S = *S0sh;

    // ---- fill box[] ----
#pragma unroll
    for (int e = 0; e < EPT; e++) {
        int j = t + e * BLK;
        float cx = p[j], cy = p[NBOX + j];
        float w_ = p[2 * NBOX + j], h_ = p[3 * NBOX + j];
        box[j] = make_float4(cx - w_ * 0.5f, cy - h_ * 0.5f,
                             cx + w_ * 0.5f, cy + h_ * 0.5f);
    }
    __syncthreads();

    // ---- stage initial batch coords + areas + zero mat ----
    if (t < NB) {
        float4 b = box[A[t]];
        bx[t] = b;
        barea[t] = (b.z - b.x) * (b.w - b.y);
    }
    ((u64*)mat)[t] = 0;
    __syncthreads();

    // ---- batched greedy loop (4 barriers/iter) ----
    while (S > 0) {
        int nb = S < NB ? S : NB;

        // (E) BALANCED lower-triangle matrix (proven exact R9-R12); areas from barea
        {
            int i = t >> 2, q = t & 3;
            if (i > 0 && i < nb) {
                int clo = (i * q) >> 2;
                int chi = (i * (q + 1)) >> 2;
                if (chi > clo) {
                    float4 bi = bx[i];
                    float ari = barea[i];
                    u64 acc = 0;
                    for (int c = clo; c < chi; c++) {
                        float4 bc = bx[c];
                        float arc = barea[c];
                        float iw = fmaxf(fminf(bi.z, bc.z) - fmaxf(bi.x, bc.x), 0.0f);
                        float ih = fmaxf(fminf(bi.w, bc.w) - fmaxf(bi.y, bc.y), 0.0f);
                        float inter = iw * ih;
                        float t2 = (ari + arc) - inter;
                        float uu = t2 + 1e-8f;
                        if ((double)inter > MND * (double)uu) acc |= (1ull << (c - clo));
                    }
                    if (acc) {
                        int w0 = clo >> 6, sh = clo & 63;
                        atomicOr(&mat[i][w0], acc << sh);
                        if (sh && (((chi - 1) >> 6) != w0))
                            atomicOr(&mat[i][w0 + 1], acc >> (64 - sh));
                    }
                }
            }
        }
        __syncthreads();  // B1

        // (G) wave 0: closure + APPLY (kom, kx, ka) + remainder tail-load
        //     waves 1-15: load tail entries
        int tailN = S - nb;
        int C1 = 0, base0 = nb;
        if (tailN > 0) {
            int lim = tailN < 7680 ? tailN : 7680;
            C1 = (lim + 959) / 960;
            base0 = nb + 960 * C1;
        }
        float4 eb[EPT]; float ea[EPT]; u16 ei[EPT];
        u32 am = 0;
        if (wid == 0) {
            u64 r0[4], r1[4], r2[4], r3[4];
#pragma unroll
            for (int wq = 0; wq < 4; wq++) {
                r0[wq] = mat[lane][wq];
                r1[wq] = mat[64 + lane][wq];
                r2[wq] = mat[128 + lane][wq];
                r3[wq] = mat[192 + lane][wq];
            }
            u64 A0, A1, A2, A3;
            {
                int n0 = nb;       A0 = n0 <= 0 ? 0ull : (n0 >= 64 ? ~0ull : ((1ull << n0) - 1ull));
                int n1 = nb - 64;  A1 = n1 <= 0 ? 0ull : (n1 >= 64 ? ~0ull : ((1ull << n1) - 1ull));
                int n2 = nb - 128; A2 = n2 <= 0 ? 0ull : (n2 >= 64 ? ~0ull : ((1ull << n2) - 1ull));
                int n3 = nb - 192; A3 = n3 <= 0 ? 0ull : (n3 >= 64 ? ~0ull : ((1ull << n3) - 1ull));
            }
            u64 K0 = 0, K1 = 0, K2 = 0, K3 = 0;
            u64 lm = (1ull << lane) - 1ull;
            while (A0 | A1 | A2 | A3) {
                bool c0b = ((A0 >> lane) & 1) && !(r0[0] & A0 & lm);
                bool c1b = ((A1 >> lane) & 1) && !((r1[0] & A0) | (r1[1] & A1 & lm));
                bool c2b = ((A2 >> lane) & 1) && !((r2[0] & A0) | (r2[1] & A1) | (r2[2] & A2 & lm));
                bool c3b = ((A3 >> lane) & 1) && !((r3[0] & A0) | (r3[1] & A1) | (r3[2] & A2) | (r3[3] & A3 & lm));
                u64 C0_ = __ballot(c0b), C1_ = __ballot(c1b), C2_ = __ballot(c2b), C3_ = __ballot(c3b);
                K0 |= C0_; K1 |= C1_; K2 |= C2_; K3 |= C3_;
                A0 &= ~C0_; A1 &= ~C1_; A2 &= ~C2_; A3 &= ~C3_;
                bool s0b = ((A0 >> lane) & 1) && ((r0[0] & C0_) | (r0[1] & C1_) | (r0[2] & C2_) | (r0[3] & C3_));
                bool s1b = ((A1 >> lane) & 1) && ((r1[0] & C0_) | (r1[1] & C1_) | (r1[2] & C2_) | (r1[3] & C3_));
                bool s2b = ((A2 >> lane) & 1) && ((r2[0] & C0_) | (r2[1] & C1_) | (r2[2] & C2_) | (r2[3] & C3_));
                bool s3b = ((A3 >> lane) & 1) && ((r3[0] & C0_) | (r3[1] & C1_) | (r3[2] & C2_) | (r3[3] & C3_));
                A0 &= ~__ballot(s0b); A1 &= ~__ballot(s1b); A2 &= ~__ballot(s2b); A3 &= ~__ballot(s3b);
            }
            if (lane < 4) keptQ[lane] = lane == 0 ? K0 : lane == 1 ? K1 : lane == 2 ? K2 : K3;
            // APPLY: each lane handles slots lane, 64+lane, 128+lane, 192+lane
            {
                int pkb1 = (int)__popcll(K0);
                int pkb2 = pkb1 + (int)__popcll(K1);
                int pkb3 = pkb2 + (int)__popcll(K2);
#pragma unroll
                for (int wq = 0; wq < 4; wq++) {
                    u64 kq = wq == 0 ? K0 : wq == 1 ? K1 : wq == 2 ? K2 : K3;
                    if ((kq >> lane) & 1) {
                        int slot = wq * 64 + lane;
                        int j = (int)A[slot];
                        atomicOr(&kom[j >> 5], 1u << (j & 31));
                        int pk = (wq == 0 ? 0 : wq == 1 ? pkb1 : wq == 2 ? pkb2 : pkb3)
                                 + (int)__popcll(kq & lm);
                        kx[pk] = bx[slot];
                        ka[pk] = barea[slot];
                    }
                }
            }
            // remainder tail-load
            if (base0 < S) {
                int C0 = (S - base0 + 63) >> 6;   // <= 4
                int st0 = base0 + lane * C0;
#pragma unroll
                for (int e = 0; e < EPT; e++) {
                    int pos = st0 + e;
                    if (e < C0 && pos < S) {
                        u16 j = A[pos];
                        ei[e] = j;
                        float4 b = box[j];
                        eb[e] = b;
                        ea[e] = (b.z - b.x) * (b.w - b.y);
                        am |= (1u << e);
                    }
                }
            }
        } else {
            int ti = t - 64;
            int st = nb + ti * C1;
#pragma unroll
            for (int e = 0; e < EPT; e++) {
                int pos = st + e;
                if (e < C1 && pos < S) {
                    u16 j = A[pos];
                    ei[e] = j;
                    float4 b = box[j];
                    eb[e] = b;
                    ea[e] = (b.z - b.x) * (b.w - b.y);
                    am |= (1u << e);
                }
            }
        }
        __syncthreads();  // B2: keptQ + kx + ka visible; closure done reading mat

        // zero mat-lower for next iter (rows 0..127; kx = rows 128..255 still live)
        if (t < 512) ((u64*)mat)[t] = 0;
        u64 kq0 = keptQ[0], kq1 = keptQ[1], kq2 = keptQ[2], kq3 = keptQ[3];
        int nk = (int)(__popcll(kq0) + __popcll(kq1) + __popcll(kq2) + __popcll(kq3));

        // (K) tail suppression: kx walk with cached areas, f64-compare, early break
        if (am) {
            for (int c = 0; c < nk; c++) {
                float4 cb = kx[c];
                float arc = ka[c];
#pragma unroll
                for (int e = 0; e < EPT; e++) {
                    if (am & (1u << e)) {
                        float iw = fminf(eb[e].z, cb.z) - fmaxf(eb[e].x, cb.x);
                        float ih = fminf(eb[e].w, cb.w) - fmaxf(eb[e].y, cb.y);
                        if (iw > 0.0f && ih > 0.0f) {
                            float inter = iw * ih;
                            float t2 = (ea[e] + arc) - inter;
                            float uu = t2 + 1e-8f;
                            if ((double)inter > MND * (double)uu) am &= ~(1u << e);
                        }
                    }
                }
                if (!am) break;
            }
        }

        // compaction: rank-order scan with wave 0 counted LAST (it holds top ranks)
        {
            int cnt = __popc(am);
            int x = cnt;
            for (int d = 1; d < 64; d <<= 1) {
                int y = __shfl_up(x, d, 64);
                if (lane >= d) x += y;
            }
            if (lane == 63) wcnt[wid] = x;
            __syncthreads();  // B4: tail walk done; kx dead
            int wb = 0, tot = 0;
            for (int i = 0; i < 16; i++) tot += wcnt[i];
            if (wid == 0) {
                for (int i = 1; i < 16; i++) wb += wcnt[i];
            } else {
                for (int i = 1; i < wid; i++) wb += wcnt[i];
            }
            int off = wb + x - cnt;
#pragma unroll
            for (int e = 0; e < EPT; e++) {
                if (am & (1u << e)) {
                    A[off] = ei[e];
                    if (off < NB) { bx[off] = eb[e]; barea[off] = ea[e]; }
                    off++;
                }
            }
            if (t >= 512) ((u64*)mat)[t] = 0;   // re-zero rows 128..255 (kx) for next iter
            __syncthreads();  // B5
            S = tot;
        }
    }
    __syncthreads();

    // ---- output: prefix over kom, scatter kept columns (pre-zeroed at entry) ----
    {
        u32 w = (t < 256) ? kom[t] : 0u;
        int c = __popc(w);
        int x = c;
        for (int d = 1; d < 64; d <<= 1) {
            int y = __shfl_up(x, d, 64);
            if (lane >= d) x += y;
        }
        if (lane == 63) wcnt[wid] = x;
        __syncthreads();
        int wb = 0;
        for (int i = 0; i < wid; i++) wb += wcnt[i];
        if (t < 256) pfxA[t] = (u32)(wb + x - c);
    }
    __syncthreads();
    for (int j = t; j < NBOX; j += BLK) {
        u32 km = kom[j >> 5];
        if ((km >> (j & 31)) & 1u) {
            int pos = (int)(pfxA[j >> 5] + (u32)__popc(km & ((1u << (j & 31)) - 1u)));
            o[0 * NBOX + pos] = p[0 * NBOX + j];
            o[1 * NBOX + pos] = p[1 * NBOX + j];
            o[2 * NBOX + pos] = p[2 * NBOX + j];
            o[3 * NBOX + pos] = p[3 * NBOX + j];
            o[4 * NBOX + pos] = p[4 * NBOX + j];
        }
    }
}

extern "C" void kernel_launch(void* const* d_in, const int* in_sizes, int n_in,
                              void* d_out, int out_size, void* d_ws, size_t ws_size,
                              hipStream_t stream) {
    const float* in = (const float*)d_in[0];
    float* out = (float*)d_out;
    int B = in_sizes[0] / (5 * NBOX);
    hipLaunchKernelGGL(nms_kernel, dim3(B), dim3(BLK), 0, stream, in, out);
}

// Round 16
// 152.192 us; speedup vs baseline: 2.1005x; 1.0075x over previous
//
#include <hip/hip_runtime.h>

#pragma clang fp contract(off)

#define NBOX 8192
#define BLK  1024
#define EPT  8
#define NBUCK 4096
#define NB 256
#define IOU_THR 0.1f

typedef unsigned short u16;
typedef unsigned int u32;
typedef unsigned long long u64;

// Exact division-free IoU threshold test:
// round_f32(inter/u) >= 0.1f  <=>  inter/u > m, m = midpoint(pred(0.1f), 0.1f).
// m = 0x1.999999p-4 exactly; m*(double)u exact in f64 -> bit-exact decision.
#define MND 0x1.999999p-4

#define SMEM_TOT 161408

__global__ __launch_bounds__(BLK, 4) void nms_kernel(const float* __restrict__ in,
                                                     float* __restrict__ out) {
    __shared__ __align__(16) char smem[SMEM_TOT];
    const int img = blockIdx.x;
    const float* __restrict__ p = in + (size_t)img * 5 * NBOX;
    float* __restrict__ o = out + (size_t)img * 5 * NBOX;
    const int t = threadIdx.x;
    const int lane = t & 63;
    const int wid = t >> 6;

    // persistent LDS
    float4* box   = (float4*)smem;                 // 128 KB: x1,y1,x2,y2 by orig idx
    u16* A        = (u16*)(smem + 131072);         // 16 KB: alive list (orig idx, rank order)
    float4* bx    = (float4*)(smem + 147456);      // 4 KB: staged batch coords (compact)
    u64 (*mat)[4] = (u64(*)[4])(smem + 151552);    // 8 KB: 256x256 lower-tri bits
    float4* kx    = (float4*)(smem + 155648);      // overlay mat rows 128..255: kept coords
    u32* pfxA     = (u32*)(smem + 151552);         // alias mat (post-loop only)
    u32* kom      = (u32*)(smem + 159744);         // 1 KB: kept bitmask by orig idx
    int* wcnt     = (int*)(smem + 160768);         // 64 B
    u64* keptQ    = (u64*)(smem + 160832);         // 32 B
    int* S0sh     = (int*)(smem + 160864);
    // sort workspace overlaying box[] (dead after ranking)
    u64* skey  = (u64*)smem;                       // 64 KB
    u32* hist  = (u32*)(smem + 65536);             // 16 KB (4096 buckets)
    u32* bbase = (u32*)(smem + 81920);             // 16 KB

    // ---- zero output up front (stores drain under the sort) ----
    {
        float4 z; z.x = z.y = z.z = z.w = 0.0f;
        float4* o4 = (float4*)o;
#pragma unroll
        for (int e = 0; e < 10; e++) o4[t + e * BLK] = z;
    }

    // ---- init ----
    for (int i = t; i < NBUCK; i += BLK) hist[i] = 0;
    if (t < 256) kom[t] = 0;
    if (t == 0) *S0sh = 0;
    __syncthreads();

    // ---- sort pass 1: bucket + arrival order ----
    u32 mybkt[EPT], myarr[EPT], mykeyhi[EPT];
#pragma unroll
    for (int e = 0; e < EPT; e++) {
        int j = t + e * BLK;
        float s = p[4 * NBOX + j];
        u32 u = __float_as_uint(s);
        u32 ordb = u ^ (u32)(((int)u >> 31) | (int)0x80000000);
        mykeyhi[e] = ~ordb;                        // ascending == score desc
        int vb = (int)(s * (float)NBUCK);
        vb = vb < 0 ? 0 : (vb > NBUCK - 1 ? NBUCK - 1 : vb);
        mybkt[e] = (u32)(NBUCK - 1 - vb);
        myarr[e] = atomicAdd(&hist[mybkt[e]], 1u);
        u64 bal = __ballot(s > 0.0f);
        if (lane == 0) atomicAdd(S0sh, (int)__popcll(bal));
    }
    __syncthreads();

    // ---- exclusive scan over hist (4 bins/thread) ----
    {
        u32 h0 = hist[4 * t], h1 = hist[4 * t + 1], h2 = hist[4 * t + 2], h3 = hist[4 * t + 3];
        int v = (int)(h0 + h1 + h2 + h3);
        int x = v;
        for (int d = 1; d < 64; d <<= 1) {
            int y = __shfl_up(x, d, 64);
            if (lane >= d) x += y;
        }
        if (lane == 63) wcnt[wid] = x;
        __syncthreads();
        int wb = 0;
        for (int i = 0; i < wid; i++) wb += wcnt[i];
        int excl = wb + x - v;
        bbase[4 * t]     = (u32)excl;
        bbase[4 * t + 1] = (u32)excl + h0;
        bbase[4 * t + 2] = (u32)excl + h0 + h1;
        bbase[4 * t + 3] = (u32)excl + h0 + h1 + h2;
    }
    __syncthreads();

    // ---- scatter keys ----
#pragma unroll
    for (int e = 0; e < EPT; e++) {
        u32 pos = bbase[mybkt[e]] + myarr[e];
        skey[pos] = ((u64)mykeyhi[e] << 32) | (u32)(t + e * BLK);
    }
    __syncthreads();

    // ---- rank within bucket -> A[rank] = orig idx ----
#pragma unroll
    for (int e = 0; e < EPT; e++) {
        u32 b = mybkt[e];
        u32 lo = bbase[b], hi2 = lo + hist[b];
        u64 me = ((u64)mykeyhi[e] << 32) | (u32)(t + e * BLK);
        u32 r = lo;
        for (u32 q = lo; q < hi2; q++) r += (skey[q] < me) ? 1u : 0u;
        A[r] = (u16)(t + e * BLK);
    }
    __syncthreads();   // sort workspace dead after this
    int S = *S0sh;

    // ---- fill box[] ----
#pragma unroll
    for (int e = 0; e < EPT; e++) {
        int j = t + e * BLK;
        float cx = p[j], cy = p[NBOX + j];
        float w_ = p[2 * NBOX + j], h_ = p[3 * NBOX + j];
        box[j] = make_float4(cx - w_ * 0.5f, cy - h_ * 0.5f,
                             cx + w_ * 0.5f, cy + h_ * 0.5f);
    }
    __syncthreads();

    // ---- stage initial batch coords + zero mat ----
    if (t < NB) bx[t] = box[A[t]];
    ((u64*)mat)[t] = 0;
    __syncthreads();

    // ---- batched greedy loop (4 barriers/iter) ----
    while (S > 0) {
        int nb = S < NB ? S : NB;

        // (E) BALANCED lower-triangle matrix (proven exact R9-R11)
        {
            int i = t >> 2, q = t & 3;
            if (i > 0 && i < nb) {
                int clo = (i * q) >> 2;
                int chi = (i * (q + 1)) >> 2;
                if (chi > clo) {
                    float4 bi = bx[i];
                    float ari = (bi.z - bi.x) * (bi.w - bi.y);
                    u64 acc = 0;
                    for (int c = clo; c < chi; c++) {
                        float4 bc = bx[c];
                        float arc = (bc.z - bc.x) * (bc.w - bc.y);
                        float iw = fmaxf(fminf(bi.z, bc.z) - fmaxf(bi.x, bc.x), 0.0f);
                        float ih = fmaxf(fminf(bi.w, bc.w) - fmaxf(bi.y, bc.y), 0.0f);
                        float inter = iw * ih;
                        float t2 = (ari + arc) - inter;
                        float uu = t2 + 1e-8f;
                        if ((double)inter > MND * (double)uu) acc |= (1ull << (c - clo));
                    }
                    if (acc) {
                        int w0 = clo >> 6, sh = clo & 63;
                        atomicOr(&mat[i][w0], acc << sh);
                        if (sh && (((chi - 1) >> 6) != w0))
                            atomicOr(&mat[i][w0 + 1], acc >> (64 - sh));
                    }
                }
            }
        }
        __syncthreads();  // B1

        // (G) wave 0: closure + APPLY (kom, kx) + remainder tail-load
        //     waves 1-15: load tail entries
        int tailN = S - nb;
        int C1 = 0, base0 = nb;
        if (tailN > 0) {
            int lim = tailN < 7680 ? tailN : 7680;
            C1 = (lim + 959) / 960;
            base0 = nb + 960 * C1;
        }
        float4 eb[EPT]; float ea[EPT]; u16 ei[EPT];
        u32 am = 0;
        if (wid == 0) {
            u64 r0[4], r1[4], r2[4], r3[4];
#pragma unroll
            for (int wq = 0; wq < 4; wq++) {
                r0[wq] = mat[lane][wq];
                r1[wq] = mat[64 + lane][wq];
                r2[wq] = mat[128 + lane][wq];
                r3[wq] = mat[192 + lane][wq];
            }
            u64 A0, A1, A2, A3;
            {
                int n0 = nb;       A0 = n0 <= 0 ? 0ull : (n0 >= 64 ? ~0ull : ((1ull << n0) - 1ull));
                int n1 = nb - 64;  A1 = n1 <= 0 ? 0ull : (n1 >= 64 ? ~0ull : ((1ull << n1) - 1ull));
                int n2 = nb - 128; A2 = n2 <= 0 ? 0ull : (n2 >= 64 ? ~0ull : ((1ull << n2) - 1ull));
                int n3 = nb - 192; A3 = n3 <= 0 ? 0ull : (n3 >= 64 ? ~0ull : ((1ull << n3) - 1ull));
            }
            u64 K0 = 0, K1 = 0, K2 = 0, K3 = 0;
            u64 lm = (1ull << lane) - 1ull;
            while (A0 | A1 | A2 | A3) {
                bool c0b = ((A0 >> lane) & 1) && !(r0[0] & A0 & lm);
                bool c1b = ((A1 >> lane) & 1) && !((r1[0] & A0) | (r1[1] & A1 & lm));
                bool c2b = ((A2 >> lane) & 1) && !((r2[0] & A0) | (r2[1] & A1) | (r2[2] & A2 & lm));
                bool c3b = ((A3 >> lane) & 1) && !((r3[0] & A0) | (r3[1] & A1) | (r3[2] & A2) | (r3[3] & A3 & lm));
                u64 C0_ = __ballot(c0b), C1_ = __ballot(c1b), C2_ = __ballot(c2b), C3_ = __ballot(c3b);
                K0 |= C0_; K1 |= C1_; K2 |= C2_; K3 |= C3_;
                A0 &= ~C0_; A1 &= ~C1_; A2 &= ~C2_; A3 &= ~C3_;
                bool s0b = ((A0 >> lane) & 1) && ((r0[0] & C0_) | (r0[1] & C1_) | (r0[2] & C2_) | (r0[3] & C3_));
                bool s1b = ((A1 >> lane) & 1) && ((r1[0] & C0_) | (r1[1] & C1_) | (r1[2] & C2_) | (r1[3] & C3_));
                bool s2b = ((A2 >> lane) & 1) && ((r2[0] & C0_) | (r2[1] & C1_) | (r2[2] & C2_) | (r2[3] & C3_));
                bool s3b = ((A3 >> lane) & 1) && ((r3[0] & C0_) | (r3[1] & C1_) | (r3[2] & C2_) | (r3[3] & C3_));
                A0 &= ~__ballot(s0b); A1 &= ~__ballot(s1b); A2 &= ~__ballot(s2b); A3 &= ~__ballot(s3b);
            }
            if (lane < 4) keptQ[lane] = lane == 0 ? K0 : lane == 1 ? K1 : lane == 2 ? K2 : K3;
            // APPLY: each lane handles slots lane, 64+lane, 128+lane, 192+lane
            {
                int pkb1 = (int)__popcll(K0);
                int pkb2 = pkb1 + (int)__popcll(K1);
                int pkb3 = pkb2 + (int)__popcll(K2);
#pragma unroll
                for (int wq = 0; wq < 4; wq++) {
                    u64 kq = wq == 0 ? K0 : wq == 1 ? K1 : wq == 2 ? K2 : K3;
                    if ((kq >> lane) & 1) {
                        int slot = wq * 64 + lane;
                        int j = (int)A[slot];
                        atomicOr(&kom[j >> 5], 1u << (j & 31));
                        int pk = (wq == 0 ? 0 : wq == 1 ? pkb1 : wq == 2 ? pkb2 : pkb3)
                                 + (int)__popcll(kq & lm);
                        kx[pk] = bx[slot];
                    }
                }
            }
            // remainder tail-load
            if (base0 < S) {
                int C0 = (S - base0 + 63) >> 6;   // <= 4
                int st0 = base0 + lane * C0;
#pragma unroll
                for (int e = 0; e < EPT; e++) {
                    int pos = st0 + e;
                    if (e < C0 && pos < S) {
                        u16 j = A[pos];
                        ei[e] = j;
                        float4 b = box[j];
                        eb[e] = b;
                        ea[e] = (b.z - b.x) * (b.w - b.y);
                        am |= (1u << e);
                    }
                }
            }
        } else {
            int ti = t - 64;
            int st = nb + ti * C1;
#pragma unroll
            for (int e = 0; e < EPT; e++) {
                int pos = st + e;
                if (e < C1 && pos < S) {
                    u16 j = A[pos];
                    ei[e] = j;
                    float4 b = box[j];
                    eb[e] = b;
                    ea[e] = (b.z - b.x) * (b.w - b.y);
                    am |= (1u << e);
                }
            }
        }
        __syncthreads();  // B2: keptQ + kx visible; closure done reading mat

        // zero mat-lower for next iter (rows 0..127; kx = rows 128..255 still live)
        if (t < 512) ((u64*)mat)[t] = 0;
        u64 kq0 = keptQ[0], kq1 = keptQ[1], kq2 = keptQ[2], kq3 = keptQ[3];
        int nk = (int)(__popcll(kq0) + __popcll(kq1) + __popcll(kq2) + __popcll(kq3));

        // (K) tail suppression: direct sequential kx walk, f64-compare, early break
        if (am) {
            for (int c = 0; c < nk; c++) {
                float4 cb = kx[c];
                float arc = (cb.z - cb.x) * (cb.w - cb.y);
#pragma unroll
                for (int e = 0; e < EPT; e++) {
                    if (am & (1u << e)) {
                        float iw = fminf(eb[e].z, cb.z) - fmaxf(eb[e].x, cb.x);
                        float ih = fminf(eb[e].w, cb.w) - fmaxf(eb[e].y, cb.y);
                        if (iw > 0.0f && ih > 0.0f) {
                            float inter = iw * ih;
                            float t2 = (ea[e] + arc) - inter;
                            float uu = t2 + 1e-8f;
                            if ((double)inter > MND * (double)uu) am &= ~(1u << e);
                        }
                    }
                }
                if (!am) break;
            }
        }

        // compaction: rank-order scan with wave 0 counted LAST (it holds top ranks)
        {
            int cnt = __popc(am);
            int x = cnt;
            for (int d = 1; d < 64; d <<= 1) {
                int y = __shfl_up(x, d, 64);
                if (lane >= d) x += y;
            }
            if (lane == 63) wcnt[wid] = x;
            __syncthreads();  // B4: tail walk done; kx dead
            int wb = 0, tot = 0;
            for (int i = 0; i < 16; i++) tot += wcnt[i];
            if (wid == 0) {
                for (int i = 1; i < 16; i++) wb += wcnt[i];
            } else {
                for (int i = 1; i < wid; i++) wb += wcnt[i];
            }
            int off = wb + x - cnt;
#pragma unroll
            for (int e = 0; e < EPT; e++) {
                if (am & (1u << e)) {
                    A[off] = ei[e];
                    if (off < NB) bx[off] = eb[e];
                    off++;
                }
            }
            if (t >= 512) ((u64*)mat)[t] = 0;   // re-zero rows 128..255 (kx) for next iter
            __syncthreads();  // B5
            S = tot;
        }
    }
    __syncthreads();

    // ---- output: prefix over kom, scatter kept columns (pre-zeroed at entry) ----
    {
        u32 w = (t < 256) ? kom[t] : 0u;
        int c = __popc(w);
        int x = c;
        for (int d = 1; d < 64; d <<= 1) {
            int y = __shfl_up(x, d, 64);
            if (lane >= d) x += y;
        }
        if (lane == 63) wcnt[wid] = x;
        __syncthreads();
        int wb = 0;
        for (int i = 0; i < wid; i++) wb += wcnt[i];
        if (t < 256) pfxA[t] = (u32)(wb + x - c);
    }
    __syncthreads();
    for (int j = t; j < NBOX; j += BLK) {
        u32 km = kom[j >> 5];
        if ((km >> (j & 31)) & 1u) {
            int pos = (int)(pfxA[j >> 5] + (u32)__popc(km & ((1u << (j & 31)) - 1u)));
            o[0 * NBOX + pos] = p[0 * NBOX + j];
            o[1 * NBOX + pos] = p[1 * NBOX + j];
            o[2 * NBOX + pos] = p[2 * NBOX + j];
            o[3 * NBOX + pos] = p[3 * NBOX + j];
            o[4 * NBOX + pos] = p[4 * NBOX + j];
        }
    }
}

extern "C" void kernel_launch(void* const* d_in, const int* in_sizes, int n_in,
                              void* d_out, int out_size, void* d_ws, size_t ws_size,
                              hipStream_t stream) {
    const float* in = (const float*)d_in[0];
    float* out = (float*)d_out;
    int B = in_sizes[0] / (5 * NBOX);
    hipLaunchKernelGGL(nms_kernel, dim3(B), dim3(BLK), 0, stream, in, out);
}